// Round 1
// baseline (167.915 us; speedup 1.0000x reference)
//
#include <hip/hip_runtime.h>

// PointPillars scatter: canvas[b, c, y, x] = feat[n, c] where coords[n] = (b, _, y, x)
// Strategy: scatter -> gather inversion.
//   K1: map[:] = -1                     (B*NY*NX ints in d_ws)
//   K2: map[b*NY*NX + y*NX + x] = n     (collision-free per problem spec)
//   K3: out[b][c][y][x] = m>=0 ? feat[m][c] : 0   (single coalesced write pass)

#define NXD 400
#define NYD 400
#define CCH 64
#define NXY (NXD * NYD)   // 160000 spatial cells per sample

__global__ void pps_init_map(int* __restrict__ map, int total) {
    int i = blockIdx.x * blockDim.x + threadIdx.x;
    int stride = gridDim.x * blockDim.x;
    for (; i < total; i += stride) map[i] = -1;
}

__global__ void pps_build_map(const int* __restrict__ coords, int* __restrict__ map, int n) {
    int i = blockIdx.x * blockDim.x + threadIdx.x;
    if (i >= n) return;
    int b = coords[i * 4 + 0];
    int y = coords[i * 4 + 2];
    int x = coords[i * 4 + 3];
    map[b * NXY + y * NXD + x] = i;
}

__global__ void pps_gather_out(const float* __restrict__ feat,
                               const int* __restrict__ map,
                               float* __restrict__ out,
                               int total_pos) {
    int pos = blockIdx.x * blockDim.x + threadIdx.x;
    if (pos >= total_pos) return;

    int b = pos / NXY;            // magic-mul div, cheap
    int s = pos - b * NXY;        // y*NX + x within the sample

    int m = map[pos];             // coalesced; reused across 64 channels via L2/L3
    float* outp = out + (size_t)b * CCH * NXY + s;

    if (m < 0) {
        // empty cell: write zeros to all 64 channel planes (wave-coalesced per plane)
        #pragma unroll
        for (int c = 0; c < CCH; ++c) {
            outp[(size_t)c * NXY] = 0.0f;
        }
    } else {
        // occupied: pillar features are 256 B contiguous -> 16x float4 loads
        const float4* f4 = (const float4*)(feat + (size_t)m * CCH);
        #pragma unroll
        for (int c4 = 0; c4 < CCH / 4; ++c4) {
            float4 v = f4[c4];
            outp[(size_t)(c4 * 4 + 0) * NXY] = v.x;
            outp[(size_t)(c4 * 4 + 1) * NXY] = v.y;
            outp[(size_t)(c4 * 4 + 2) * NXY] = v.z;
            outp[(size_t)(c4 * 4 + 3) * NXY] = v.w;
        }
    }
}

extern "C" void kernel_launch(void* const* d_in, const int* in_sizes, int n_in,
                              void* d_out, int out_size, void* d_ws, size_t ws_size,
                              hipStream_t stream) {
    const float* feat  = (const float*)d_in[0];   // [N, 64] fp32
    const int* coords  = (const int*)d_in[1];     // [N, 4] int32 (b, _, y, x)
    float* out         = (float*)d_out;           // [B, 64, NY, NX] fp32

    const int n_pillars = in_sizes[1] / 4;
    const int batch     = out_size / (CCH * NXY); // B from output size (host-side)
    const int total_pos = batch * NXY;            // 1.28M spatial cells

    int* map = (int*)d_ws;                        // needs batch*NXY*4 = 5.12 MB

    // K1: reset map every call (d_ws is not re-poisoned between replays,
    // so we must re-init for determinism)
    {
        int block = 256;
        int grid = 2048;
        pps_init_map<<<grid, block, 0, stream>>>(map, total_pos);
    }
    // K2: scatter pillar indices into the map
    {
        int block = 256;
        int grid = (n_pillars + block - 1) / block;
        pps_build_map<<<grid, block, 0, stream>>>(coords, map, n_pillars);
    }
    // K3: gather pass — one thread per spatial cell, writes all 64 channels
    {
        int block = 256;
        int grid = (total_pos + block - 1) / block;
        pps_gather_out<<<grid, block, 0, stream>>>(feat, map, out, total_pos);
    }
}

// Round 2
// 90.630 us; speedup vs baseline: 1.8527x; 1.8527x over previous
//
#include <hip/hip_runtime.h>

// PointPillars scatter: canvas[b, c, y, x] = feat[n, c] where coords[n] = (b, _, y, x)
// Strategy: scatter -> gather inversion, float4-vectorized output pass.
//   K1: map[:] = -1                     (B*NY*NX ints in d_ws)
//   K2: map[b*NY*NX + y*NX + x] = n     (collision-free per problem spec)
//   K3: each thread owns 4 consecutive x-positions; loads its 4 map entries
//       once (int4 -> registers), then writes one float4 per channel plane.
//       Wave-instruction = 1 KB contiguous store (vs 256 B in R1) -> streams.

#define NXD 400
#define NYD 400
#define CCH 64
#define NXY (NXD * NYD)   // 160000 spatial cells per sample (divisible by 4)

__global__ void pps_init_map(int* __restrict__ map, int total) {
    int i = blockIdx.x * blockDim.x + threadIdx.x;
    int stride = gridDim.x * blockDim.x;
    for (; i < total; i += stride) map[i] = -1;
}

__global__ void pps_build_map(const int* __restrict__ coords, int* __restrict__ map, int n) {
    int i = blockIdx.x * blockDim.x + threadIdx.x;
    if (i >= n) return;
    int4 c4 = ((const int4*)coords)[i];   // (b, _, y, x)
    map[c4.x * NXY + c4.z * NXD + c4.w] = i;
}

__global__ __launch_bounds__(256) void pps_gather_out(const float* __restrict__ feat,
                                                      const int* __restrict__ map,
                                                      float* __restrict__ out,
                                                      int total_pos) {
    int t = blockIdx.x * blockDim.x + threadIdx.x;
    int pos4 = t * 4;                   // first of this thread's 4 positions
    if (pos4 >= total_pos) return;

    int4 m = *(const int4*)(map + pos4);   // 16B coalesced, kept in registers

    int b = pos4 / NXY;                 // all 4 positions share b (NXY % 4 == 0)
    int s = pos4 - b * NXY;
    float* outp = out + (size_t)b * CCH * NXY + s;

    const bool o0 = m.x >= 0, o1 = m.y >= 0, o2 = m.z >= 0, o3 = m.w >= 0;
    const float* f0 = feat + (size_t)m.x * CCH;   // only dereferenced if o* true
    const float* f1 = feat + (size_t)m.y * CCH;
    const float* f2 = feat + (size_t)m.z * CCH;
    const float* f3 = feat + (size_t)m.w * CCH;

    #pragma unroll 8
    for (int c = 0; c < CCH; ++c) {
        float4 v;
        v.x = o0 ? f0[c] : 0.0f;        // exec-masked gathers; feat is L3-resident
        v.y = o1 ? f1[c] : 0.0f;
        v.z = o2 ? f2[c] : 0.0f;
        v.w = o3 ? f3[c] : 0.0f;
        *(float4*)(outp + (size_t)c * NXY) = v;   // 16B/lane -> 1KB/wave contiguous
    }
}

extern "C" void kernel_launch(void* const* d_in, const int* in_sizes, int n_in,
                              void* d_out, int out_size, void* d_ws, size_t ws_size,
                              hipStream_t stream) {
    const float* feat  = (const float*)d_in[0];   // [N, 64] fp32
    const int* coords  = (const int*)d_in[1];     // [N, 4] int32 (b, _, y, x)
    float* out         = (float*)d_out;           // [B, 64, NY, NX] fp32

    const int n_pillars = in_sizes[1] / 4;
    const int batch     = out_size / (CCH * NXY);
    const int total_pos = batch * NXY;            // 1.28M spatial cells

    int* map = (int*)d_ws;                        // batch*NXY*4 = 5.12 MB

    // K1: reset map every call (d_ws not re-poisoned between replays)
    pps_init_map<<<2048, 256, 0, stream>>>(map, total_pos);

    // K2: scatter pillar indices into the map
    pps_build_map<<<(n_pillars + 255) / 256, 256, 0, stream>>>(coords, map, n_pillars);

    // K3: gather pass — one thread per 4 spatial cells, float4 stores per plane
    {
        int threads = total_pos / 4;              // 320000
        pps_gather_out<<<(threads + 255) / 256, 256, 0, stream>>>(feat, map, out, total_pos);
    }
}

// Round 4
// 89.079 us; speedup vs baseline: 1.8850x; 1.0174x over previous
//
#include <hip/hip_runtime.h>

// PointPillars scatter: canvas[b, c, y, x] = feat[n, c] where coords[n] = (b, _, y, x)
// Strategy: scatter -> gather inversion.
//   K1: map[:] = -1                     (B*NY*NX ints in d_ws, int4 nt stores)
//   K2: map[b*NY*NX + y*NX + x] = n     (collision-free per problem spec)
//   K3: thread owns 4 consecutive x-cells. Per channel-quad: 4x float4 gather
//       (empty slots clamped to pillar 0 + cndmask-zeroed), 4x4 register
//       transpose, 4x float4 nontemporal plane-stores. Block=1024 gives each
//       channel plane a 16KB contiguous run per block.
// Note: __builtin_nontemporal_* requires native vector types, not
// HIP_vector_type classes -> use ext_vector_type aliases.

#define NXD 400
#define NYD 400
#define CCH 64
#define NXY (NXD * NYD)   // 160000 cells/sample, divisible by 4

typedef float fvec4 __attribute__((ext_vector_type(4)));
typedef int   ivec4 __attribute__((ext_vector_type(4)));

__global__ void pps_init_map(ivec4* __restrict__ map4, int total4) {
    int i = blockIdx.x * blockDim.x + threadIdx.x;
    int stride = gridDim.x * blockDim.x;
    ivec4 neg1 = {-1, -1, -1, -1};
    for (; i < total4; i += stride)
        __builtin_nontemporal_store(neg1, map4 + i);
}

__global__ void pps_build_map(const int* __restrict__ coords, int* __restrict__ map, int n) {
    int i = blockIdx.x * blockDim.x + threadIdx.x;
    if (i >= n) return;
    ivec4 c4 = *(const ivec4*)(coords + i * 4);   // (b, _, y, x)
    map[c4.x * NXY + c4.z * NXD + c4.w] = i;
}

__global__ __launch_bounds__(1024) void pps_gather_out(const float* __restrict__ feat,
                                                       const int* __restrict__ map,
                                                       float* __restrict__ out,
                                                       int total_pos) {
    int t = blockIdx.x * blockDim.x + threadIdx.x;
    int pos4 = t * 4;
    if (pos4 >= total_pos) return;

    ivec4 m = __builtin_nontemporal_load((const ivec4*)(map + pos4)); // single-use

    int b = pos4 / NXY;                  // 4 cells never straddle a sample (NXY%4==0)
    int s = pos4 - b * NXY;
    float* outp = out + (size_t)b * CCH * NXY + s;

    const bool o0 = m.x >= 0, o1 = m.y >= 0, o2 = m.z >= 0, o3 = m.w >= 0;
    // Clamp empty slots to pillar 0: valid memory, broadcast cache line.
    const fvec4* f0 = (const fvec4*)(feat + (size_t)(o0 ? m.x : 0) * CCH);
    const fvec4* f1 = (const fvec4*)(feat + (size_t)(o1 ? m.y : 0) * CCH);
    const fvec4* f2 = (const fvec4*)(feat + (size_t)(o2 ? m.z : 0) * CCH);
    const fvec4* f3 = (const fvec4*)(feat + (size_t)(o3 ? m.w : 0) * CCH);

    const fvec4 zero = {0.f, 0.f, 0.f, 0.f};

    #pragma unroll 4
    for (int g = 0; g < CCH / 4; ++g) {   // channel quad c = 4g..4g+3
        fvec4 a0 = f0[g];                 // unconditional wide loads
        fvec4 a1 = f1[g];
        fvec4 a2 = f2[g];
        fvec4 a3 = f3[g];
        if (!o0) a0 = zero;               // v_cndmask x4
        if (!o1) a1 = zero;
        if (!o2) a2 = zero;
        if (!o3) a3 = zero;
        // transpose: plane c=4g+k gets {cell0[k], cell1[k], cell2[k], cell3[k]}
        fvec4 v0 = {a0.x, a1.x, a2.x, a3.x};
        fvec4 v1 = {a0.y, a1.y, a2.y, a3.y};
        fvec4 v2 = {a0.z, a1.z, a2.z, a3.z};
        fvec4 v3 = {a0.w, a1.w, a2.w, a3.w};
        __builtin_nontemporal_store(v0, (fvec4*)(outp + (size_t)(4 * g + 0) * NXY));
        __builtin_nontemporal_store(v1, (fvec4*)(outp + (size_t)(4 * g + 1) * NXY));
        __builtin_nontemporal_store(v2, (fvec4*)(outp + (size_t)(4 * g + 2) * NXY));
        __builtin_nontemporal_store(v3, (fvec4*)(outp + (size_t)(4 * g + 3) * NXY));
    }
}

extern "C" void kernel_launch(void* const* d_in, const int* in_sizes, int n_in,
                              void* d_out, int out_size, void* d_ws, size_t ws_size,
                              hipStream_t stream) {
    const float* feat  = (const float*)d_in[0];   // [N, 64] fp32
    const int* coords  = (const int*)d_in[1];     // [N, 4] int32 (b, _, y, x)
    float* out         = (float*)d_out;           // [B, 64, NY, NX] fp32

    const int n_pillars = in_sizes[1] / 4;
    const int batch     = out_size / (CCH * NXY);
    const int total_pos = batch * NXY;            // 1.28M cells

    int* map = (int*)d_ws;                        // batch*NXY*4 = 5.12 MB

    // K1: reset map every call (d_ws not re-poisoned between replays)
    pps_init_map<<<1024, 256, 0, stream>>>((ivec4*)map, total_pos / 4);

    // K2: scatter pillar indices into the map
    pps_build_map<<<(n_pillars + 255) / 256, 256, 0, stream>>>(coords, map, n_pillars);

    // K3: gather pass — one thread per 4 cells, float4 nt stores per plane
    {
        int threads = total_pos / 4;              // 320000
        pps_gather_out<<<(threads + 1023) / 1024, 1024, 0, stream>>>(feat, map, out, total_pos);
    }
}